// Round 7
// baseline (54.601 us; speedup 1.0000x reference)
//
#include <hip/hip_runtime.h>

#define DD 128
#define HH 160
#define WW 128
#define BB 4
#define HW  (HH * WW)            // 20480
#define DHW (DD * HW)

#define TX 64
#define TY 4
#define TZ 4
#define XT (WW / TX)             // 2
#define YT (HH / TY)             // 40
#define ZT (DD / TZ)             // 32
#define NWG (XT * YT * ZT * BB)  // 10240
#define NXCD 8
#define CPX (NWG / NXCD)         // 1280
#define LDSF 12800               // floats (51.2 KB -> 3 blocks/CU)

static_assert(XT == 2 && ZT == 32 && NWG % NXCD == 0, "layout assumptions");

typedef float f4 __attribute__((ext_vector_type(4), aligned(4)));
typedef float f2 __attribute__((ext_vector_type(2), aligned(4)));
typedef float v2 __attribute__((ext_vector_type(2)));

__global__ __launch_bounds__(256)
void st_affine_kernel(const float* __restrict__ src,
                      const float* __restrict__ aff,
                      float* __restrict__ out) {
    __shared__ float lds[LDSF];

    // XCD-aware bijective swizzle; lin order: x-tile fastest, y-tile, z-tile, b
    const int wgid = blockIdx.x;
    const int lin  = (wgid & (NXCD - 1)) * CPX + (wgid >> 3);
    const int xt = lin & 1;
    const int l2 = lin >> 1;
    const int yt = l2 % YT;
    const int l3 = l2 / YT;
    const int zt = l3 & (ZT - 1);
    const int b  = l3 >> 5;
    const int x0t = xt * TX, y0t = yt * TY, z0t = zt * TZ;

    const float* A = aff + b * 12;   // uniform -> scalar loads
    const float cD = 128.f / 127.f, cH = 160.f / 159.f, cW = 128.f / 127.f;
    // fold normalize/unnormalize into coefficients: i = P.z*z + P.y*y + P.x*x + Pc
    const float pz0 = A[0] * cD, pz1 = A[1] * cD, pz2 = A[2]  * cD, pz3 = fmaf(A[3],  cD, -0.5f);
    const float py0 = A[4] * cH, py1 = A[5] * cH, py2 = A[6]  * cH, py3 = fmaf(A[7],  cH, -0.5f);
    const float px0 = A[8] * cW, px1 = A[9] * cW, px2 = A[10] * cW, px3 = fmaf(A[11], cW, -0.5f);

    // ---- bbox of needed src cells over the 8 tile corners ----
    // (same fma nesting as per-output coords => bitwise-consistent; +-1 margin)
    float mnx = 1e30f, mxx = -1e30f, mny = 1e30f, mxy = -1e30f, mnz = 1e30f, mxz = -1e30f;
#pragma unroll
    for (int ci = 0; ci < 8; ++ci) {
        float czc = (float)(z0t + ((ci & 1) ? TZ - 1 : 0));
        float cyc = (float)(y0t + ((ci & 2) ? TY - 1 : 0));
        float cxc = (float)(x0t + ((ci & 4) ? TX - 1 : 0));
        float iz = fmaf(pz0, czc, fmaf(pz1, cyc, fmaf(pz2, cxc, pz3)));
        float iy = fmaf(py0, czc, fmaf(py1, cyc, fmaf(py2, cxc, py3)));
        float ix = fmaf(px0, czc, fmaf(px1, cyc, fmaf(px2, cxc, px3)));
        mnz = fminf(mnz, iz); mxz = fmaxf(mxz, iz);
        mny = fminf(mny, iy); mxy = fmaxf(mxy, iy);
        mnx = fminf(mnx, ix); mxx = fmaxf(mxx, ix);
    }
    mnx = __builtin_amdgcn_fmed3f(mnx, 0.f, 127.f); mxx = __builtin_amdgcn_fmed3f(mxx, 0.f, 127.f);
    mny = __builtin_amdgcn_fmed3f(mny, 0.f, 159.f); mxy = __builtin_amdgcn_fmed3f(mxy, 0.f, 159.f);
    mnz = __builtin_amdgcn_fmed3f(mnz, 0.f, 127.f); mxz = __builtin_amdgcn_fmed3f(mxz, 0.f, 127.f);
    const int xlo = max(0, (int)floorf(mnx) - 1);
    const int ylo = max(0, (int)floorf(mny) - 1);
    const int zlo = max(0, (int)floorf(mnz) - 1);
    const int xhi = min(WW - 2, (int)floorf(mxx) + 1);   // max cell base
    const int yhi = min(HH - 2, (int)floorf(mxy) + 1);
    const int zhi = min(DD - 2, (int)floorf(mxz) + 1);
    const int XE = xhi - xlo + 2;
    const int YE = yhi - ylo + 2;
    const int ZE = zhi - zlo + 2;
    const int pitch = (XE + 3) & ~3;
    const int nRows = YE * ZE;
    const int slice = YE * pitch;

    bool fits = (XE <= 128) && (nRows * pitch <= LDSF);
    // staging reads 16B chunks; guard the 12B global overrun at the very end of src
    if (b == BB - 1 && zhi == DD - 2 && yhi == HH - 2 && xhi >= WW - 4) fits = false;

    const int tid  = threadIdx.x;
    const int lane = tid & 63;
    const int wid  = tid >> 6;

    // ---- per-output coords: 4 outputs along z, packed as two v2 pairs ----
    const int ox = x0t + lane;
    const int oy = y0t + wid;
    const float fx = (float)ox, fy = (float)oy;
    const float Sz = fmaf(pz1, fy, fmaf(pz2, fx, pz3));
    const float Sy = fmaf(py1, fy, fmaf(py2, fx, py3));
    const float Sx = fmaf(px1, fy, fmaf(px2, fx, px3));
    const float fz = (float)z0t;

    v2 izA = {fmaf(pz0, fz,       Sz), fmaf(pz0, fz + 1.f, Sz)};
    v2 izB = {fmaf(pz0, fz + 2.f, Sz), fmaf(pz0, fz + 3.f, Sz)};
    v2 iyA = {fmaf(py0, fz,       Sy), fmaf(py0, fz + 1.f, Sy)};
    v2 iyB = {fmaf(py0, fz + 2.f, Sy), fmaf(py0, fz + 3.f, Sy)};
    v2 ixA = {fmaf(px0, fz,       Sx), fmaf(px0, fz + 1.f, Sx)};
    v2 ixB = {fmaf(px0, fz + 2.f, Sx), fmaf(px0, fz + 3.f, Sx)};

    auto clamp2 = [](v2 v, float hi) {
        v2 r; r.x = __builtin_amdgcn_fmed3f(v.x, 0.f, hi);
              r.y = __builtin_amdgcn_fmed3f(v.y, 0.f, hi); return r;
    };
    // cell base = min(floor(ic), S-2); weight = ic - base (border fold: w->1 at top edge)
    v2 wzA, wzB, wyA, wyB, wxA, wxB;
    v2 izcA = clamp2(izA, 127.f), izcB = clamp2(izB, 127.f);
    v2 iycA = clamp2(iyA, 159.f), iycB = clamp2(iyB, 159.f);
    v2 ixcA = clamp2(ixA, 127.f), ixcB = clamp2(ixB, 127.f);
    v2 z0A = {fminf(floorf(izcA.x), 126.f), fminf(floorf(izcA.y), 126.f)};
    v2 z0B = {fminf(floorf(izcB.x), 126.f), fminf(floorf(izcB.y), 126.f)};
    v2 y0A = {fminf(floorf(iycA.x), 158.f), fminf(floorf(iycA.y), 158.f)};
    v2 y0B = {fminf(floorf(iycB.x), 158.f), fminf(floorf(iycB.y), 158.f)};
    v2 x0A = {fminf(floorf(ixcA.x), 126.f), fminf(floorf(ixcA.y), 126.f)};
    v2 x0B = {fminf(floorf(ixcB.x), 126.f), fminf(floorf(ixcB.y), 126.f)};
    wzA = izcA - z0A; wzB = izcB - z0B;
    wyA = iycA - y0A; wyB = iycB - y0B;
    wxA = ixcA - x0A; wxB = ixcB - x0B;

    v2 rA, rB;
    if (fits) {
        // ---- stage bbox rows into LDS, async (one row per wave per issue) ----
        {
            const float* sb = src + b * DHW;
            const bool act = (lane * 4) < XE;
            int r = wid, yi = wid;
            int gofs = zlo * HW + ylo * WW + xlo + lane * 4 + yi * WW;
            const int wrapAdj = HW - YE * WW;
            int zi_wrap = 0; (void)zi_wrap;
            while (yi >= YE) { yi -= YE; gofs += wrapAdj; }
            int lofs = r * pitch;
            for (; r < nRows; r += 4) {
                if (act) {
#if __has_builtin(__builtin_amdgcn_global_load_lds)
                    __builtin_amdgcn_global_load_lds(
                        (const __attribute__((address_space(1))) void*)(sb + gofs),
                        (__attribute__((address_space(3))) void*)(&lds[lofs]), 16, 0, 0);
#else
                    *(f4*)(&lds[lofs + lane * 4]) = *(const f4*)(sb + gofs);
#endif
                }
                yi += 4; gofs += 4 * WW; lofs += 4 * pitch;
                while (yi >= YE) { yi -= YE; gofs += wrapAdj; }
            }
        }
        __syncthreads();

        const float zloF = (float)zlo, yloF = (float)ylo, xloF = (float)xlo;
        const float YEf = (float)YE, pitchF = (float)pitch;
        auto offl = [&](float zc, float yc, float xc) -> int {
            // ((zi*YE + yi)*pitch + xi), exact in fp32 (all ints < 2^23)
            return (int)fmaf(fmaf(zc - zloF, YEf, yc - yloF), pitchF, xc - xloF);
        };
        auto samp = [&](int o, float wxs, float wys, float wzs) -> float {
            f2 v00 = *(const f2*)(lds + o);
            f2 v01 = *(const f2*)(lds + o + pitch);
            f2 v10 = *(const f2*)(lds + o + slice);
            f2 v11 = *(const f2*)(lds + o + slice + pitch);
            float c00 = fmaf(v00.y - v00.x, wxs, v00.x);
            float c01 = fmaf(v01.y - v01.x, wxs, v01.x);
            float c10 = fmaf(v10.y - v10.x, wxs, v10.x);
            float c11 = fmaf(v11.y - v11.x, wxs, v11.x);
            float c0 = fmaf(c01 - c00, wys, c00);
            float c1 = fmaf(c11 - c10, wys, c10);
            return fmaf(c1 - c0, wzs, c0);
        };
        rA.x = samp(offl(z0A.x, y0A.x, x0A.x), wxA.x, wyA.x, wzA.x);
        rA.y = samp(offl(z0A.y, y0A.y, x0A.y), wxA.y, wyA.y, wzA.y);
        rB.x = samp(offl(z0B.x, y0B.x, x0B.x), wxB.x, wyB.x, wzB.x);
        rB.y = samp(offl(z0B.y, y0B.y, x0B.y), wxB.y, wyB.y, wzB.y);
    } else {
        // ---- direct global gather fallback (rare; exact same math) ----
        const float* sb = src + b * DHW;
        auto sampg = [&](float zc, float yc, float xc, float wxs, float wys, float wzs) -> float {
            int o = (int)fmaf(zc, (float)HW, fmaf(yc, (float)WW, xc));
            const float* p = sb + o;
            f2 v00 = *(const f2*)(p);
            f2 v01 = *(const f2*)(p + WW);
            f2 v10 = *(const f2*)(p + HW);
            f2 v11 = *(const f2*)(p + HW + WW);
            float c00 = fmaf(v00.y - v00.x, wxs, v00.x);
            float c01 = fmaf(v01.y - v01.x, wxs, v01.x);
            float c10 = fmaf(v10.y - v10.x, wxs, v10.x);
            float c11 = fmaf(v11.y - v11.x, wxs, v11.x);
            float c0 = fmaf(c01 - c00, wys, c00);
            float c1 = fmaf(c11 - c10, wys, c10);
            return fmaf(c1 - c0, wzs, c0);
        };
        rA.x = sampg(z0A.x, y0A.x, x0A.x, wxA.x, wyA.x, wzA.x);
        rA.y = sampg(z0A.y, y0A.y, x0A.y, wxA.y, wyA.y, wzA.y);
        rB.x = sampg(z0B.x, y0B.x, x0B.x, wxB.x, wyB.x, wzB.x);
        rB.y = sampg(z0B.y, y0B.y, x0B.y, wxB.y, wyB.y, wzB.y);
    }

    float* dst = out + (size_t)(((b * DD + z0t) * HH + oy) * WW + ox);
    __builtin_nontemporal_store(rA.x, dst);
    __builtin_nontemporal_store(rA.y, dst + HW);
    __builtin_nontemporal_store(rB.x, dst + 2 * HW);
    __builtin_nontemporal_store(rB.y, dst + 3 * HW);
}

extern "C" void kernel_launch(void* const* d_in, const int* in_sizes, int n_in,
                              void* d_out, int out_size, void* d_ws, size_t ws_size,
                              hipStream_t stream) {
    const float* src = (const float*)d_in[0];
    const float* aff = (const float*)d_in[1];
    float* out = (float*)d_out;

    st_affine_kernel<<<dim3(NWG), dim3(256), 0, stream>>>(src, aff, out);
}

// Round 8
// 28.448 us; speedup vs baseline: 1.9193x; 1.9193x over previous
//
#include <hip/hip_runtime.h>

#define DD 128
#define HH 160
#define WW 128
#define BB 4
#define HW  20480
#define DHW 2621440

#define TX 64
#define TY 8
#define TZ 4
#define YT (HH / TY)             // 20
#define ZT (DD / TZ)             // 32
#define NWG (2 * YT * ZT * BB)   // 5120
#define NXCD 8
#define CPX (NWG / NXCD)         // 640
#define LDSF 12800               // floats (51.2 KB -> 3 blocks/CU)
#define MAXCH (LDSF / 4)         // 3200 16B chunks

typedef float f2 __attribute__((ext_vector_type(2), aligned(4)));
typedef float v2 __attribute__((ext_vector_type(2)));

__global__ __launch_bounds__(256)
void st_affine_kernel(const float* __restrict__ src,
                      const float* __restrict__ aff,
                      float* __restrict__ out) {
    __shared__ float lds[LDSF];

    // XCD-aware bijective swizzle
    const int wgid = blockIdx.x;
    const int lin  = (wgid & (NXCD - 1)) * CPX + (wgid >> 3);
    const int xt = lin & 1;
    const int l2 = lin >> 1;
    const int yt = l2 % YT;
    const int l3 = l2 / YT;
    const int zt = l3 & (ZT - 1);
    const int b  = l3 >> 5;
    const int x0t = xt * TX, y0t = yt * TY, z0t = zt * TZ;

    const float* A = aff + b * 12;   // uniform -> scalar loads
    const float cD = 128.f / 127.f, cH = 160.f / 159.f, cW = 128.f / 127.f;
    const float pz0 = A[0] * cD, pz1 = A[1] * cD, pz2 = A[2]  * cD, pz3 = fmaf(A[3],  cD, -0.5f);
    const float py0 = A[4] * cH, py1 = A[5] * cH, py2 = A[6]  * cH, py3 = fmaf(A[7],  cH, -0.5f);
    const float px0 = A[8] * cW, px1 = A[9] * cW, px2 = A[10] * cW, px3 = fmaf(A[11], cW, -0.5f);

    // ---- bbox of needed src cells over the 8 tile corners (±1 margin) ----
    float mnx = 1e30f, mxx = -1e30f, mny = 1e30f, mxy = -1e30f, mnz = 1e30f, mxz = -1e30f;
#pragma unroll
    for (int ci = 0; ci < 8; ++ci) {
        float czc = (float)(z0t + ((ci & 1) ? TZ - 1 : 0));
        float cyc = (float)(y0t + ((ci & 2) ? TY - 1 : 0));
        float cxc = (float)(x0t + ((ci & 4) ? TX - 1 : 0));
        float iz = fmaf(pz0, czc, fmaf(pz1, cyc, fmaf(pz2, cxc, pz3)));
        float iy = fmaf(py0, czc, fmaf(py1, cyc, fmaf(py2, cxc, py3)));
        float ix = fmaf(px0, czc, fmaf(px1, cyc, fmaf(px2, cxc, px3)));
        mnz = fminf(mnz, iz); mxz = fmaxf(mxz, iz);
        mny = fminf(mny, iy); mxy = fmaxf(mxy, iy);
        mnx = fminf(mnx, ix); mxx = fmaxf(mxx, ix);
    }
    mnx = __builtin_amdgcn_fmed3f(mnx, 0.f, 127.f); mxx = __builtin_amdgcn_fmed3f(mxx, 0.f, 127.f);
    mny = __builtin_amdgcn_fmed3f(mny, 0.f, 159.f); mxy = __builtin_amdgcn_fmed3f(mxy, 0.f, 159.f);
    mnz = __builtin_amdgcn_fmed3f(mnz, 0.f, 127.f); mxz = __builtin_amdgcn_fmed3f(mxz, 0.f, 127.f);
    const int xlo = max(0, (int)floorf(mnx) - 1);
    const int ylo = max(0, (int)floorf(mny) - 1);
    const int zlo = max(0, (int)floorf(mnz) - 1);
    const int xhi = min(WW - 2, (int)floorf(mxx) + 1);   // max cell base
    const int yhi = min(HH - 2, (int)floorf(mxy) + 1);
    const int zhi = min(DD - 2, (int)floorf(mxz) + 1);

    const int xlo4  = xlo & ~3;              // 16B-aligned staging window
    const int XE4   = xhi - xlo4 + 2;        // floats needed per row
    const int YE    = yhi - ylo + 2;
    const int ZE    = zhi - zlo + 2;
    const int pitch = (XE4 + 3) & ~3;        // row pitch (mult of 4 floats)
    const int cpr   = pitch >> 2;            // 16B chunks per row
    const int nRows = YE * ZE;
    const int slice = YE * pitch;
    const int spp   = slice + pitch;
    const int totalChunks = nRows * cpr;
    const bool fits = (totalChunks <= MAXCH);

    const int tid  = threadIdx.x;
    const int lane = tid & 63;
    const int wid  = tid >> 6;

    // ---- output mapping: 2 x per thread, y from (wid, lane>>5), z-chain of 4
    const int xp = x0t + ((lane & 31) << 1);
    const int yo = y0t + (wid << 1) + (lane >> 5);
    const float fx0 = (float)xp, fx1 = (float)(xp + 1);
    const float fy = (float)yo, fz = (float)z0t;

    // coords at z = z0t for both x's; z-step adds p*0
    const float izb0 = fmaf(pz0, fz, fmaf(pz1, fy, fmaf(pz2, fx0, pz3)));
    const float izb1 = fmaf(pz0, fz, fmaf(pz1, fy, fmaf(pz2, fx1, pz3)));
    const float iyb0 = fmaf(py0, fz, fmaf(py1, fy, fmaf(py2, fx0, py3)));
    const float iyb1 = fmaf(py0, fz, fmaf(py1, fy, fmaf(py2, fx1, py3)));
    const float ixb0 = fmaf(px0, fz, fmaf(px1, fy, fmaf(px2, fx0, px3)));
    const float ixb1 = fmaf(px0, fz, fmaf(px1, fy, fmaf(px2, fx1, px3)));

    // ---- dense staging: chunk k -> (row, x-chunk); per-lane GLOBAL addr,
    // linear LDS dest (wave-uniform base + lane*16), all 64 lanes active ----
    if (fits) {
        const float rcpr = 1.0f / (float)cpr;
        const float rYE  = 1.0f / (float)YE;
        const float cprF = (float)cpr, YEf = (float)YE;
        const float zloF = (float)zlo, yloF = (float)ylo, xlo4F = (float)xlo4;
        const float* sb = src + b * DHW;
        const int nIt = (totalChunks + 255) >> 8;
        for (int it = 0; it < nIt; ++it) {
            const int k = (it << 8) + (wid << 6) + lane;
            if (k < totalChunks) {
                float kf   = (float)k;
                float rowf = floorf(fmaf(kf, rcpr, 0.5f * rcpr));   // k / cpr (exact)
                float xif  = fmaf(-rowf, cprF, kf);                 // k % cpr (exact)
                float zif  = floorf(fmaf(rowf, rYE, 0.5f * rYE));   // row / YE
                float yif  = fmaf(-zif, YEf, rowf);                 // row % YE
                float gf   = fmaf(zloF + zif, 20480.f,
                             fmaf(yloF + yif, 128.f,
                             fmaf(xif, 4.f, xlo4F)));               // exact (<2^23)
                int g = min((int)gf, DHW - 4);                      // end-of-volume pad guard
                __builtin_amdgcn_global_load_lds(
                    (const __attribute__((address_space(1))) void*)(sb + g),
                    (__attribute__((address_space(3))) void*)(lds + (size_t)(((it << 8) + (wid << 6)) << 2)),
                    16, 0, 0);
            }
        }
    }
    __syncthreads();

    const float zloF = (float)zlo, yloF = (float)ylo, xlo4F = (float)xlo4;
    const float YEf = (float)YE, pitchF = (float)pitch;

    float* dst = out + (size_t)(((b * DD + z0t) * HH + yo) * WW + xp);

    if (fits) {
        auto sampL = [&](float iz, float iy, float ix) -> float {
            iz = __builtin_amdgcn_fmed3f(iz, 0.f, 127.f);
            iy = __builtin_amdgcn_fmed3f(iy, 0.f, 159.f);
            ix = __builtin_amdgcn_fmed3f(ix, 0.f, 127.f);
            float z0 = fminf(floorf(iz), 126.f);
            float y0 = fminf(floorf(iy), 158.f);
            float x0 = fminf(floorf(ix), 126.f);
            float wz = iz - z0, wy = iy - y0, wx = ix - x0;
            int o = (int)fmaf(fmaf(z0 - zloF, YEf, y0 - yloF), pitchF, x0 - xlo4F);
            f2 v00 = *(const f2*)(lds + o);
            f2 v01 = *(const f2*)(lds + o + pitch);
            f2 v10 = *(const f2*)(lds + o + slice);
            f2 v11 = *(const f2*)(lds + o + spp);
            float c00 = fmaf(v00.y - v00.x, wx, v00.x);
            float c01 = fmaf(v01.y - v01.x, wx, v01.x);
            float c10 = fmaf(v10.y - v10.x, wx, v10.x);
            float c11 = fmaf(v11.y - v11.x, wx, v11.x);
            float c0 = fmaf(c01 - c00, wy, c00);
            float c1 = fmaf(c11 - c10, wy, c10);
            return fmaf(c1 - c0, wz, c0);
        };
#pragma unroll
        for (int k = 0; k < TZ; ++k) {
            const float kf = (float)k;
            v2 r;
            r.x = sampL(fmaf(kf, pz0, izb0), fmaf(kf, py0, iyb0), fmaf(kf, px0, ixb0));
            r.y = sampL(fmaf(kf, pz0, izb1), fmaf(kf, py0, iyb1), fmaf(kf, px0, ixb1));
            __builtin_nontemporal_store(r, (v2*)(dst + k * HW));
        }
    } else {
        // direct-gather fallback (rare oversized-bbox blocks; same math)
        const float* sb = src + b * DHW;
        auto sampG = [&](float iz, float iy, float ix) -> float {
            iz = __builtin_amdgcn_fmed3f(iz, 0.f, 127.f);
            iy = __builtin_amdgcn_fmed3f(iy, 0.f, 159.f);
            ix = __builtin_amdgcn_fmed3f(ix, 0.f, 127.f);
            float z0 = fminf(floorf(iz), 126.f);
            float y0 = fminf(floorf(iy), 158.f);
            float x0 = fminf(floorf(ix), 126.f);
            float wz = iz - z0, wy = iy - y0, wx = ix - x0;
            int o = (int)fmaf(z0, 20480.f, fmaf(y0, 128.f, x0));
            const float* p = sb + o;
            f2 v00 = *(const f2*)(p);
            f2 v01 = *(const f2*)(p + WW);
            f2 v10 = *(const f2*)(p + HW);
            f2 v11 = *(const f2*)(p + HW + WW);
            float c00 = fmaf(v00.y - v00.x, wx, v00.x);
            float c01 = fmaf(v01.y - v01.x, wx, v01.x);
            float c10 = fmaf(v10.y - v10.x, wx, v10.x);
            float c11 = fmaf(v11.y - v11.x, wx, v11.x);
            float c0 = fmaf(c01 - c00, wy, c00);
            float c1 = fmaf(c11 - c10, wy, c10);
            return fmaf(c1 - c0, wz, c0);
        };
#pragma unroll
        for (int k = 0; k < TZ; ++k) {
            const float kf = (float)k;
            v2 r;
            r.x = sampG(fmaf(kf, pz0, izb0), fmaf(kf, py0, iyb0), fmaf(kf, px0, ixb0));
            r.y = sampG(fmaf(kf, pz0, izb1), fmaf(kf, py0, iyb1), fmaf(kf, px0, ixb1));
            __builtin_nontemporal_store(r, (v2*)(dst + k * HW));
        }
    }
}

extern "C" void kernel_launch(void* const* d_in, const int* in_sizes, int n_in,
                              void* d_out, int out_size, void* d_ws, size_t ws_size,
                              hipStream_t stream) {
    const float* src = (const float*)d_in[0];
    const float* aff = (const float*)d_in[1];
    float* out = (float*)d_out;

    st_affine_kernel<<<dim3(NWG), dim3(256), 0, stream>>>(src, aff, out);
}

// Round 9
// 28.011 us; speedup vs baseline: 1.9493x; 1.0156x over previous
//
#include <hip/hip_runtime.h>

#define DD 128
#define HH 160
#define WW 128
#define BB 4
#define HW  20480
#define DHW 2621440

#define TX 32
#define TY 16
#define TZ 4
#define XT (WW / TX)             // 4
#define YT (HH / TY)             // 10
#define ZT (DD / TZ)             // 32
#define NWG (XT * YT * ZT * BB)  // 5120
#define NXCD 8
#define CPX (NWG / NXCD)         // 640
#define LDSF 10240               // floats = 40.96 KB  -> up to 4 blocks/CU
#define MAXCH (LDSF / 4)         // 2560 16B chunks

typedef float f2 __attribute__((ext_vector_type(2), aligned(4)));
typedef float v2 __attribute__((ext_vector_type(2)));

__global__ __launch_bounds__(512)
void st_affine_kernel(const float* __restrict__ src,
                      const float* __restrict__ aff,
                      float* __restrict__ out) {
    __shared__ float lds[LDSF];

    // XCD-aware bijective swizzle (NWG % 8 == 0)
    const int wgid = blockIdx.x;
    const int lin  = (wgid & (NXCD - 1)) * CPX + (wgid >> 3);
    const int xt = lin & 3;
    const int l2 = lin >> 2;
    const int yt = l2 % YT;
    const int l3 = l2 / YT;
    const int zt = l3 & 31;
    const int b  = l3 >> 5;
    const int x0t = xt * TX, y0t = yt * TY, z0t = zt * TZ;

    const float* A = aff + b * 12;   // uniform -> scalar loads
    const float cD = 128.f/127.f, cH = 160.f/159.f, cW = 128.f/127.f;
    const float pz0 = A[0]*cD, pz1 = A[1]*cD, pz2 = A[2]*cD,  pz3 = fmaf(A[3],  cD, -0.5f);
    const float py0 = A[4]*cH, py1 = A[5]*cH, py2 = A[6]*cH,  py3 = fmaf(A[7],  cH, -0.5f);
    const float px0 = A[8]*cW, px1 = A[9]*cW, px2 = A[10]*cW, px3 = fmaf(A[11], cW, -0.5f);

    // ---- bbox of a linear map over a box: center +- sum(|coef|*halfext) ----
    const float hz = (TZ - 1) * 0.5f, hy = (TY - 1) * 0.5f, hx = (TX - 1) * 0.5f;
    const float ccz = (float)z0t + hz, ccy = (float)y0t + hy, ccx = (float)x0t + hx;
    const float izc = fmaf(pz0, ccz, fmaf(pz1, ccy, fmaf(pz2, ccx, pz3)));
    const float iyc = fmaf(py0, ccz, fmaf(py1, ccy, fmaf(py2, ccx, py3)));
    const float ixc = fmaf(px0, ccz, fmaf(px1, ccy, fmaf(px2, ccx, px3)));
    const float rz = fmaf(fabsf(pz0), hz, fmaf(fabsf(pz1), hy, fmaf(fabsf(pz2), hx, 1e-3f)));
    const float ry = fmaf(fabsf(py0), hz, fmaf(fabsf(py1), hy, fmaf(fabsf(py2), hx, 1e-3f)));
    const float rx = fmaf(fabsf(px0), hz, fmaf(fabsf(px1), hy, fmaf(fabsf(px2), hx, 1e-3f)));
    const float mnz = izc - rz, mxz = izc + rz;
    const float mny = iyc - ry, mxy = iyc + ry;
    const float mnx = ixc - rx, mxx = ixc + rx;

    // interior: every sample strictly inside [0, S-1) -> all clamps are no-ops
    const bool interior =
        (mnz > 0.02f) && (mxz < 126.98f) &&
        (mny > 0.02f) && (mxy < 158.98f) &&
        (mnx > 0.02f) && (mxx < 126.98f);

    const int xlo = max(0, (int)floorf(__builtin_amdgcn_fmed3f(mnx, 0.f, 127.f)) - 1);
    const int ylo = max(0, (int)floorf(__builtin_amdgcn_fmed3f(mny, 0.f, 159.f)) - 1);
    const int zlo = max(0, (int)floorf(__builtin_amdgcn_fmed3f(mnz, 0.f, 127.f)) - 1);
    const int xhi = min(WW - 2, (int)floorf(__builtin_amdgcn_fmed3f(mxx, 0.f, 127.f)) + 1);
    const int yhi = min(HH - 2, (int)floorf(__builtin_amdgcn_fmed3f(mxy, 0.f, 159.f)) + 1);
    const int zhi = min(DD - 2, (int)floorf(__builtin_amdgcn_fmed3f(mxz, 0.f, 127.f)) + 1);

    const int xlo4  = xlo & ~3;
    const int XE4   = xhi - xlo4 + 2;
    const int YE    = yhi - ylo + 2;
    const int ZE    = zhi - zlo + 2;
    const int pitch = (XE4 + 3) & ~3;
    const int cpr   = pitch >> 2;
    const int slice = YE * pitch;
    const int totalChunks = ZE * YE * cpr;

    bool fits = (totalChunks <= MAXCH);
    // exclude the few blocks whose staged window touches the very end of src
    // (16B staging chunks would need the address clamp on REAL data there)
    if (b == BB - 1 && zhi >= DD - 3 && yhi >= HH - 3 && xhi >= WW - 7) fits = false;

    const int tid  = threadIdx.x;
    const int lane = tid & 63;
    const int wid  = tid >> 6;

    // ---- dense full-wave staging: chunk k -> (z,y,x-chunk) of bbox ----
    if (fits) {
        const float rcpr = 1.f / (float)cpr, rYE = 1.f / (float)YE;
        const float cprF = (float)cpr, YEfS = (float)YE;
        const float zloF = (float)zlo, yloF = (float)ylo, xlo4F = (float)xlo4;
        const float* sb = src + b * DHW;
        const int nIt = (totalChunks + 511) >> 9;     // <= 5
        for (int it = 0; it < nIt; ++it) {
            const int k = (it << 9) + tid;            // no predicate: overshoot
            float kf   = (float)k;                    // chunks clamp + land in
            float rowf = floorf(fmaf(kf, rcpr, 0.5f * rcpr));   // unused LDS
            float xif  = fmaf(-rowf, cprF, kf);
            float zif  = floorf(fmaf(rowf, rYE, 0.5f * rYE));
            float yif  = fmaf(-zif, YEfS, rowf);
            float gf   = fmaf(zloF + zif, 20480.f,
                         fmaf(yloF + yif, 128.f,
                         fmaf(xif, 4.f, xlo4F)));     // exact in fp32 (<2^23)
            int g = min((int)gf, DHW - 4);
            __builtin_amdgcn_global_load_lds(
                (const __attribute__((address_space(1))) void*)(sb + g),
                (__attribute__((address_space(3))) void*)(lds + (size_t)(((it << 9) + (wid << 6)) * 4)),
                16, 0, 0);
        }
    }
    __syncthreads();

    // ---- outputs: 2 x (pair) x 2 z per thread ----
    const int xp = x0t + ((lane & 15) << 1);
    const int yo = y0t + ((lane >> 4) | ((wid & 3) << 2));
    const int zb = z0t + ((wid >> 2) << 1);
    const float fx0 = (float)xp, fy = (float)yo, fzb = (float)zb;

    const float izb0 = fmaf(pz0, fzb, fmaf(pz1, fy, fmaf(pz2, fx0, pz3)));
    const float iyb0 = fmaf(py0, fzb, fmaf(py1, fy, fmaf(py2, fx0, py3)));
    const float ixb0 = fmaf(px0, fzb, fmaf(px1, fy, fmaf(px2, fx0, px3)));
    const float izb1 = izb0 + pz2, iyb1 = iyb0 + py2, ixb1 = ixb0 + px2;

    const float zloF = (float)zlo, yloF = (float)ylo, xlo4F = (float)xlo4;
    const float YEf = (float)YE, pitchF = (float)pitch;
    float* dst = out + (size_t)(((b * DD + zb) * HH + yo) * WW + xp);

    auto lerpL = [&](int o, float wxs, float wys, float wzs) -> float {
        f2 v00 = *(const f2*)(lds + o);
        f2 v01 = *(const f2*)(lds + o + pitch);
        f2 v10 = *(const f2*)(lds + o + slice);
        f2 v11 = *(const f2*)(lds + o + slice + pitch);
        float c00 = fmaf(v00.y - v00.x, wxs, v00.x);
        float c01 = fmaf(v01.y - v01.x, wxs, v01.x);
        float c10 = fmaf(v10.y - v10.x, wxs, v10.x);
        float c11 = fmaf(v11.y - v11.x, wxs, v11.x);
        float c0 = fmaf(c01 - c00, wys, c00);
        float c1 = fmaf(c11 - c10, wys, c10);
        return fmaf(c1 - c0, wzs, c0);
    };
    auto lerpG = [&](float cz, float cy, float cx, float wxs, float wys, float wzs) -> float {
        int o = (int)fmaf(cz, 20480.f, fmaf(cy, 128.f, cx));
        const float* p = src + b * DHW + o;
        f2 v00 = *(const f2*)(p);
        f2 v01 = *(const f2*)(p + WW);
        f2 v10 = *(const f2*)(p + HW);
        f2 v11 = *(const f2*)(p + HW + WW);
        float c00 = fmaf(v00.y - v00.x, wxs, v00.x);
        float c01 = fmaf(v01.y - v01.x, wxs, v01.x);
        float c10 = fmaf(v10.y - v10.x, wxs, v10.x);
        float c11 = fmaf(v11.y - v11.x, wxs, v11.x);
        float c0 = fmaf(c01 - c00, wys, c00);
        float c1 = fmaf(c11 - c10, wys, c10);
        return fmaf(c1 - c0, wzs, c0);
    };

#pragma unroll
    for (int kq = 0; kq < 2; ++kq) {
        const float kf = (float)kq;
        float iz0 = fmaf(kf, pz0, izb0), iz1 = fmaf(kf, pz0, izb1);
        float iy0 = fmaf(kf, py0, iyb0), iy1 = fmaf(kf, py0, iyb1);
        float ix0 = fmaf(kf, px0, ixb0), ix1 = fmaf(kf, px0, ixb1);
        float cz0, cy0, cx0, cz1, cy1, cx1;
        if (interior) {
            cz0 = floorf(iz0); cz1 = floorf(iz1);
            cy0 = floorf(iy0); cy1 = floorf(iy1);
            cx0 = floorf(ix0); cx1 = floorf(ix1);
        } else {
            iz0 = __builtin_amdgcn_fmed3f(iz0, 0.f, 127.f);
            iz1 = __builtin_amdgcn_fmed3f(iz1, 0.f, 127.f);
            iy0 = __builtin_amdgcn_fmed3f(iy0, 0.f, 159.f);
            iy1 = __builtin_amdgcn_fmed3f(iy1, 0.f, 159.f);
            ix0 = __builtin_amdgcn_fmed3f(ix0, 0.f, 127.f);
            ix1 = __builtin_amdgcn_fmed3f(ix1, 0.f, 127.f);
            cz0 = fminf(floorf(iz0), 126.f); cz1 = fminf(floorf(iz1), 126.f);
            cy0 = fminf(floorf(iy0), 158.f); cy1 = fminf(floorf(iy1), 158.f);
            cx0 = fminf(floorf(ix0), 126.f); cx1 = fminf(floorf(ix1), 126.f);
        }
        const float wz0 = iz0 - cz0, wz1 = iz1 - cz1;
        const float wy0 = iy0 - cy0, wy1 = iy1 - cy1;
        const float wx0 = ix0 - cx0, wx1 = ix1 - cx1;

        v2 r;
        if (fits) {
            int o0 = (int)fmaf(fmaf(cz0 - zloF, YEf, cy0 - yloF), pitchF, cx0 - xlo4F);
            int o1 = (int)fmaf(fmaf(cz1 - zloF, YEf, cy1 - yloF), pitchF, cx1 - xlo4F);
            r.x = lerpL(o0, wx0, wy0, wz0);
            r.y = lerpL(o1, wx1, wy1, wz1);
        } else {
            r.x = lerpG(cz0, cy0, cx0, wx0, wy0, wz0);
            r.y = lerpG(cz1, cy1, cx1, wx1, wy1, wz1);
        }
        __builtin_nontemporal_store(r, (v2*)(dst + kq * HW));
    }
}

extern "C" void kernel_launch(void* const* d_in, const int* in_sizes, int n_in,
                              void* d_out, int out_size, void* d_ws, size_t ws_size,
                              hipStream_t stream) {
    const float* src = (const float*)d_in[0];
    const float* aff = (const float*)d_in[1];
    float* out = (float*)d_out;

    st_affine_kernel<<<dim3(NWG), dim3(512), 0, stream>>>(src, aff, out);
}